// Round 7
// baseline (392.444 us; speedup 1.0000x reference)
//
#include <hip/hip_runtime.h>

typedef unsigned short u16;
typedef unsigned int u32;
typedef short short8 __attribute__((ext_vector_type(8)));
typedef u16 u16x8 __attribute__((ext_vector_type(8)));
typedef u16 u16x4 __attribute__((ext_vector_type(4)));
typedef float f32x4 __attribute__((ext_vector_type(4)));
typedef float f32x16 __attribute__((ext_vector_type(16)));

__device__ __forceinline__ u16 f2bf(float f) {
  u32 u = __builtin_bit_cast(u32, f);
  u += 0x7fff + ((u >> 16) & 1);   // RNE
  return (u16)(u >> 16);
}
__device__ __forceinline__ float ex2(float x) {      // 2^x, single v_exp_f32
  float r; asm("v_exp_f32 %0, %1" : "=v"(r) : "v"(x)); return r;
}
__device__ __forceinline__ u32 cvtpk(float lo, float hi) {   // packed bf16 (RNE)
  u32 r; asm("v_cvt_pk_bf16_f32 %0, %1, %2" : "=v"(r) : "v"(lo), "v"(hi)); return r;
}

// async global->LDS 16B (m97 idiom). LDS dest = wave-uniform base + lane*16.
__device__ __forceinline__ void gload16(const void* g, void* l) {
  __builtin_amdgcn_global_load_lds(
      (const __attribute__((address_space(1))) u32*)(unsigned long long)g,
      (__attribute__((address_space(3))) u32*)(u32)(unsigned long long)l,
      16, 0, 0);
}

// ---------------- f32 -> bf16 convert (weights only now) ----------------
__global__ __launch_bounds__(256) void cvt4(const float* __restrict__ a, const float* __restrict__ b,
                                            const float* __restrict__ c, const float* __restrict__ d0,
                                            u16* __restrict__ oa, u16* __restrict__ ob,
                                            u16* __restrict__ oc, u16* __restrict__ od, int n4) {
  const int z = blockIdx.y;
  const float* s = z == 0 ? a : (z == 1 ? b : (z == 2 ? c : d0));
  u16* d = z == 0 ? oa : (z == 1 ? ob : (z == 2 ? oc : od));
  int i = blockIdx.x * 256 + threadIdx.x;
  if (i >= n4) return;
  float4 f = reinterpret_cast<const float4*>(s)[i];
  u16x4 o;
  o.x = f2bf(f.x); o.y = f2bf(f.y); o.z = f2bf(f.z); o.w = f2bf(f.w);
  reinterpret_cast<u16x4*>(d)[i] = o;
}

// ---------------- GEMM: C = A * B^T + bias. BMx128 tile, BK=32 ----------------
// Counted-vmcnt pipeline: 3 LDS buffers, 2-ahead prefetch, raw s_barrier,
// steady-state wait leaves newest tile's loads in flight (never vmcnt(0) mid-loop).
// AF32: A staged as f32 via global_load_lds (pre-swizzled source, rule 21),
// converted to bf16 at frag-read via v_cvt_pk_bf16_f32. LDS A swizzle:
// phys 16B-chunk = logical ^ (row & 7)  (both sides).
// bf16 path LDS swizzle: logical k-chunk c of row r stored at phys c^((r>>1)&3).
template <int BM, bool AF32>
__device__ __forceinline__ void gemm_core(const void* __restrict__ Ap, const u16* __restrict__ Bm,
                                          const float* __restrict__ bias, u16* __restrict__ Cb,
                                          float* __restrict__ Cf, int K, int ldc, int ccol0,
                                          float cs, int m0, int n0) {
  constexpr int MI = BM / 32;                  // row frags per wave (4 or 2)
  __shared__ __align__(16) u16 As[3][AF32 ? BM * 64 : BM * 32];
  __shared__ __align__(16) u16 Bs[3][128 * 32];
  const int t = threadIdx.x, l = t & 63, w = t >> 6;
  const int lg = l >> 4, lr = l & 15;
  const int wr = (w >> 1) * (16 * MI), wc = (w & 1) * 64;
  const int srowB = w * 32 + (l >> 2);
  const int scol = ((l & 3) ^ ((l >> 3) & 3)) * 8;   // pre-swizzled source chunk (bf16 path)
  const u16* gb = Bm + (size_t)(n0 + srowB) * K + scol;
  const int ldstB = w * 1024 + l * 8;
  const int ko = (lg ^ ((lr >> 1) & 3)) * 8;         // swizzled frag chunk (bf16 path)

  // bf16-A path maps (BM=64 only here)
  const int srowA = w * 16 + (l >> 2);
  const u16* ga = (const u16*)Ap + (size_t)(m0 + srowA) * K + scol;
  const int ldstA = w * 512 + l * 8;
  // f32-A path maps: lane covers row (l>>3), phys chunk l&7; source pre-swizzled
  const float* gaf = (const float*)Ap +
      (size_t)(m0 + w * 32 + (l >> 3)) * K + (((l & 7) ^ (l >> 3)) * 4);

  u16* a0 = &As[0][0]; u16* a1 = &As[1][0]; u16* a2 = &As[2][0];
  u16* b0 = &Bs[0][0]; u16* b1 = &Bs[1][0]; u16* b2 = &Bs[2][0];

  auto stage = [&](int kk, u16* ab, u16* bb) {
    gload16(gb + kk, bb + ldstB);
    gload16(gb + kk + 16 * (size_t)K, bb + ldstB + 512);
    if constexpr (AF32) {
#pragma unroll
      for (int c = 0; c < 4; ++c)
        gload16(gaf + kk + (size_t)(c * 8) * K,
                (float*)ab + (w * 32 + c * 8) * 32 + l * 4);
    } else {
      gload16(ga + kk, ab + ldstA);
      if constexpr (BM == 128) gload16(ga + kk + 16 * (size_t)K, ab + ldstA + 512);
    }
  };
  auto wait_counted = [&]() {   // leave newest tile's loads outstanding
    if constexpr (AF32)            asm volatile("s_waitcnt vmcnt(6)" ::: "memory");
    else if constexpr (BM == 128)  asm volatile("s_waitcnt vmcnt(4)" ::: "memory");
    else                           asm volatile("s_waitcnt vmcnt(3)" ::: "memory");
  };

  f32x4 acc[MI][4];
#pragma unroll
  for (int i = 0; i < MI; ++i)
#pragma unroll
    for (int jj = 0; jj < 4; ++jj) acc[i][jj] = (f32x4){0.f, 0.f, 0.f, 0.f};

  const int ni = K >> 5;
  stage(0, a0, b0);
  stage(32, a1, b1);
  wait_counted();                                    // tile 0 landed
  __builtin_amdgcn_s_barrier();
  __builtin_amdgcn_sched_barrier(0);

  for (int it = 0; it < ni; ++it) {
    const bool pf = (it + 2) < ni;
    if (pf) stage((it + 2) << 5, a2, b2);
    short8 af[MI], bf[4];
#pragma unroll
    for (int i = 0; i < MI; ++i) {
      if constexpr (AF32) {
        const float* abuf = (const float*)a0;
        const int arow = wr + 16 * i + lr;
        const int s7 = arow & 7;
        f32x4 u = *reinterpret_cast<const f32x4*>(abuf + arow * 32 + ((2 * lg) ^ s7) * 4);
        f32x4 v = *reinterpret_cast<const f32x4*>(abuf + arow * 32 + ((2 * lg + 1) ^ s7) * 4);
        union { u32 x[4]; short8 s; } pk;
        pk.x[0] = cvtpk(u[0], u[1]); pk.x[1] = cvtpk(u[2], u[3]);
        pk.x[2] = cvtpk(v[0], v[1]); pk.x[3] = cvtpk(v[2], v[3]);
        af[i] = pk.s;
      } else {
        af[i] = *reinterpret_cast<const short8*>(&a0[(wr + 16 * i + lr) * 32 + ko]);
      }
    }
#pragma unroll
    for (int jj = 0; jj < 4; ++jj)
      bf[jj] = *reinterpret_cast<const short8*>(&b0[(wc + 16 * jj + lr) * 32 + ko]);
    __builtin_amdgcn_s_setprio(1);
#pragma unroll
    for (int i = 0; i < MI; ++i)
#pragma unroll
      for (int jj = 0; jj < 4; ++jj)
        acc[i][jj] = __builtin_amdgcn_mfma_f32_16x16x32_bf16(af[i], bf[jj], acc[i][jj], 0, 0, 0);
    __builtin_amdgcn_s_setprio(0);
    if (it + 1 < ni) {
      if (pf) wait_counted();                        // tile it+1 landed
      else    asm volatile("s_waitcnt vmcnt(0)" ::: "memory");
      __builtin_amdgcn_s_barrier();
      __builtin_amdgcn_sched_barrier(0);
    }
    u16* tmp;
    tmp = a0; a0 = a1; a1 = a2; a2 = tmp;
    tmp = b0; b0 = b1; b1 = b2; b2 = tmp;
  }

  // C layout (16x16x32): col=lane&15, row=(lane>>4)*4+r  [m89/m91]
#pragma unroll
  for (int i = 0; i < MI; ++i) {
#pragma unroll
    for (int jj = 0; jj < 4; ++jj) {
      int col = n0 + wc + 16 * jj + lr;
      float bv = bias[col];
#pragma unroll
      for (int r = 0; r < 4; ++r) {
        int row = m0 + wr + 16 * i + lg * 4 + r;
        float val = (acc[i][jj][r] + bv) * cs;
        if (Cb) Cb[(size_t)row * ldc + ccol0 + col] = f2bf(val);
        else    Cf[(size_t)row * ldc + col] = val;
      }
    }
  }
}

// Q output pre-scaled by log2(e)/8 so attention softmax runs in exp2 domain.
#define QSCALE 0.18033688011112042f

// QKV projections: A read directly as f32 (fused cvt), XCD-chunked swizzle.
__global__ __launch_bounds__(256) void gemm_qkv(const float* __restrict__ q, const float* __restrict__ k,
                                                const float* __restrict__ v, const u16* __restrict__ Wq,
                                                const u16* __restrict__ Wk, const u16* __restrict__ Wv,
                                                const float* __restrict__ bq, const float* __restrict__ bk,
                                                const float* __restrict__ bv, u16* __restrict__ QKV) {
  const int hw = blockIdx.x + 8 * (blockIdx.y + 64 * blockIdx.z);   // 0..1535
  const int lgid = (hw & 7) * 192 + (hw >> 3);                      // XCD-chunked bijection
  const int n0 = (lgid & 7) * 128;
  const int m0 = ((lgid >> 3) & 63) * 128;
  const int z = lgid >> 9;
  const float* A = z == 0 ? q : (z == 1 ? k : v);
  const u16* B = z == 0 ? Wq : (z == 1 ? Wk : Wv);
  const float* bias = z == 0 ? bq : (z == 1 ? bk : bv);
  gemm_core<128, true>(A, B, bias, QKV, nullptr, 1024, 3072, z * 1024,
                       z == 0 ? QSCALE : 1.0f, m0, n0);
}

__global__ __launch_bounds__(256) void gemm_out(const u16* __restrict__ AO, const u16* __restrict__ Wo,
                                                const float* __restrict__ bo, float* __restrict__ out) {
  const int hw = blockIdx.x + 8 * blockIdx.y;                       // 0..1023
  const int lgid = (hw & 7) * 128 + (hw >> 3);
  const int n0 = (lgid & 7) * 128;
  const int m0 = (lgid >> 3) * 64;
  gemm_core<64, false>(AO, Wo, bo, nullptr, out, 1024, 1024, 0, 1.0f, m0, n0);
}

// ---------------- Flash attention (causal), dbuf KV, joint-64 softmax ----------------
// (round-6 verbatim: passed, ~<79us) 4 waves x 32 q-rows, grid (64,16) LPT,
// KV tile 64 double-buffered -> one barrier/tile; joint softmax over 64 kv.
#define LDK 72
#define DEFER_THR 11.0f

__global__ __launch_bounds__(256, 3) void attn_fwd(const u16* __restrict__ QKV, u16* __restrict__ O) {
  __shared__ __align__(16) u16 Kt[2][64 * LDK];
  __shared__ __align__(16) u16 Vt[2][64 * LDK];   // transposed [d][kv]

  const int t = threadIdx.x, l = t & 63, w = t >> 6;
  const int lq = l & 31, hi = l >> 5;
  const int bh = blockIdx.x;                   // 0..63
  const int qb = 15 - (int)blockIdx.y;         // 15..0, longest blocks first
  const int b = bh >> 4, h = bh & 15;
  const size_t rowb = (size_t)b * 2048;
  const int qcol = h * 64, kcol = 1024 + h * 64, vcol = 2048 + h * 64;
  const int q0w = qb * 128 + 32 * w;           // this wave's 32 q rows
  const int nt = 2 * qb + 2;                   // KV tiles of 64

  short8 qf[4];
  {
    const u16* qp = QKV + (rowb + q0w + lq) * 3072 + qcol + hi * 8;
#pragma unroll
    for (int ks = 0; ks < 4; ++ks) qf[ks] = *reinterpret_cast<const short8*>(qp + ks * 16);
  }

  f32x16 oa[2];
#pragma unroll
  for (int dt = 0; dt < 2; ++dt)
#pragma unroll
    for (int r = 0; r < 16; ++r) oa[dt][r] = 0.f;
  float m_run = -1e30f, l_run = 0.f;

  const int kr = t & 31, kc = (t >> 5) * 8;    // t>>5 in 0..7
  short8 ka0, ka1;
  u16x8 va0, va1;

  auto stage_load = [&](int kv64) {
    const u16* kp = QKV + (rowb + (size_t)kv64 * 64 + kr) * 3072 + kcol + kc;
    ka0 = *reinterpret_cast<const short8*>(kp);
    ka1 = *reinterpret_cast<const short8*>(kp + 32 * 3072);
    const u16* vp = QKV + (rowb + (size_t)kv64 * 64 + 2 * kr) * 3072 + vcol + kc;
    va0 = *reinterpret_cast<const u16x8*>(vp);
    va1 = *reinterpret_cast<const u16x8*>(vp + 3072);
  };
  auto stage_write = [&](int buf) {
    *reinterpret_cast<short8*>(&Kt[buf][kr * LDK + kc]) = ka0;
    *reinterpret_cast<short8*>(&Kt[buf][(kr + 32) * LDK + kc]) = ka1;
#pragma unroll
    for (int jj = 0; jj < 8; ++jj) {
      u32 pk = (u32)va0[jj] | ((u32)va1[jj] << 16);
      *reinterpret_cast<u32*>(&Vt[buf][(kc + jj) * LDK + 2 * kr]) = pk;
    }
  };

  auto packP = [&](const f32x16& p, short8 pf[2]) {
    u32 P[8], X[8];
#pragma unroll
    for (int m2 = 0; m2 < 8; ++m2) {
      P[m2] = cvtpk(p[2 * m2], p[2 * m2 + 1]);
      X[m2] = (u32)__shfl_xor((int)P[m2], 32);
    }
#pragma unroll
    for (int ks2 = 0; ks2 < 2; ++ks2) {
      union { u32 u[4]; short8 v; } uu;
      uu.u[0] = hi ? X[4 * ks2 + 2] : P[4 * ks2 + 0];
      uu.u[1] = hi ? X[4 * ks2 + 3] : P[4 * ks2 + 1];
      uu.u[2] = hi ? P[4 * ks2 + 2] : X[4 * ks2 + 0];
      uu.u[3] = hi ? P[4 * ks2 + 3] : X[4 * ks2 + 1];
      pf[ks2] = uu.v;
    }
  };
  auto pvStep = [&](const u16* Vtc, int kt32, const short8 pf[2]) {
    __builtin_amdgcn_s_setprio(1);
#pragma unroll
    for (int ks2 = 0; ks2 < 2; ++ks2)
#pragma unroll
      for (int dt = 0; dt < 2; ++dt) {
        short8 vf = *reinterpret_cast<const short8*>(
            &Vtc[(dt * 32 + lq) * LDK + kt32 + ks2 * 16 + hi * 8]);
        oa[dt] = __builtin_amdgcn_mfma_f32_32x32x16_bf16(vf, pf[ks2], oa[dt], 0, 0, 0);
      }
    __builtin_amdgcn_s_setprio(0);
  };
  auto rescale_sum = [&](float pm) {
    if (!__all(pm <= m_run + DEFER_THR)) {         // T13 threshold defer
      float mnew = fmaxf(m_run, pm);
      float al = ex2(m_run - mnew);
      l_run *= al;
#pragma unroll
      for (int dt = 0; dt < 2; ++dt)
#pragma unroll
        for (int r = 0; r < 16; ++r) oa[dt][r] *= al;
      m_run = mnew;
    }
  };

  auto flash2 = [&](const u16* Ktc, const u16* Vtc, bool diag1) {
    f32x16 s0, s1;
#pragma unroll
    for (int r = 0; r < 16; ++r) { s0[r] = 0.f; s1[r] = 0.f; }
    __builtin_amdgcn_s_setprio(1);
#pragma unroll
    for (int ks = 0; ks < 4; ++ks) {
      short8 kf = *reinterpret_cast<const short8*>(&Ktc[lq * LDK + ks * 16 + hi * 8]);
      s0 = __builtin_amdgcn_mfma_f32_32x32x16_bf16(kf, qf[ks], s0, 0, 0, 0);
    }
#pragma unroll
    for (int ks = 0; ks < 4; ++ks) {
      short8 kf = *reinterpret_cast<const short8*>(&Ktc[(32 + lq) * LDK + ks * 16 + hi * 8]);
      s1 = __builtin_amdgcn_mfma_f32_32x32x16_bf16(kf, qf[ks], s1, 0, 0, 0);
    }
    __builtin_amdgcn_s_setprio(0);
    if (diag1) {
#pragma unroll
      for (int r = 0; r < 16; ++r) {
        int off = (r & 3) + 8 * (r >> 2) + 4 * hi;
        if (off > lq) s1[r] = -1e30f;
      }
    }
    float pm = fmaxf(s0[0], s1[0]);
#pragma unroll
    for (int r = 1; r < 16; ++r) pm = fmaxf(pm, fmaxf(s0[r], s1[r]));
    pm = fmaxf(pm, __shfl_xor(pm, 32));
    rescale_sum(pm);
    float ps = 0.f;
#pragma unroll
    for (int r = 0; r < 16; ++r) { float e = ex2(s0[r] - m_run); s0[r] = e; ps += e; }
#pragma unroll
    for (int r = 0; r < 16; ++r) { float e = ex2(s1[r] - m_run); s1[r] = e; ps += e; }
    ps += __shfl_xor(ps, 32);
    l_run += ps;
    short8 pf[2];
    packP(s0, pf);
    pvStep(Vtc, 0, pf);        // PV(s0) MFMA overlaps pack(s1) VALU
    packP(s1, pf);
    pvStep(Vtc, 32, pf);
  };

  auto flash1 = [&](const u16* Ktc, const u16* Vtc) {
    f32x16 s;
#pragma unroll
    for (int r = 0; r < 16; ++r) s[r] = 0.f;
    __builtin_amdgcn_s_setprio(1);
#pragma unroll
    for (int ks = 0; ks < 4; ++ks) {
      short8 kf = *reinterpret_cast<const short8*>(&Ktc[lq * LDK + ks * 16 + hi * 8]);
      s = __builtin_amdgcn_mfma_f32_32x32x16_bf16(kf, qf[ks], s, 0, 0, 0);
    }
    __builtin_amdgcn_s_setprio(0);
#pragma unroll
    for (int r = 0; r < 16; ++r) {
      int off = (r & 3) + 8 * (r >> 2) + 4 * hi;
      if (off > lq) s[r] = -1e30f;
    }
    float pm = s[0];
#pragma unroll
    for (int r = 1; r < 16; ++r) pm = fmaxf(pm, s[r]);
    pm = fmaxf(pm, __shfl_xor(pm, 32));
    rescale_sum(pm);
    float ps = 0.f;
#pragma unroll
    for (int r = 0; r < 16; ++r) { float e = ex2(s[r] - m_run); s[r] = e; ps += e; }
    ps += __shfl_xor(ps, 32);
    l_run += ps;
    short8 pf[2];
    packP(s, pf);
    pvStep(Vtc, 0, pf);
  };

  stage_load(0);
  stage_write(0);
  __syncthreads();

  for (int kb = 0; kb < nt; ++kb) {
    const int cur = kb & 1;
    const u16* Ktc = &Kt[cur][0];
    const u16* Vtc = &Vt[cur][0];
    if (kb + 1 < nt) stage_load(kb + 1);        // T14: issue loads before compute
    const int rel = q0w - kb * 64;
    if (rel >= 32)      flash2(Ktc, Vtc, rel == 32);
    else if (rel == 0)  flash1(Ktc, Vtc);
    if (kb + 1 < nt) stage_write(cur ^ 1);      // write OTHER buffer: no read race
    __syncthreads();                            // single barrier per tile
  }

  const float inv = __builtin_amdgcn_rcpf(l_run);
  const size_t obase = (rowb + q0w + lq) * 1024 + h * 64;
#pragma unroll
  for (int dt = 0; dt < 2; ++dt) {
    u32 Bp[8], Xb[8];
#pragma unroll
    for (int m2 = 0; m2 < 8; ++m2) {
      Bp[m2] = cvtpk(oa[dt][2 * m2] * inv, oa[dt][2 * m2 + 1] * inv);
      Xb[m2] = (u32)__shfl_xor((int)Bp[m2], 32);
    }
    if (hi == dt) {
#pragma unroll
      for (int c = 0; c < 4; ++c) {
        union { u32 u[4]; short8 v; } uu;
        uu.u[0] = hi ? Xb[2 * c]     : Bp[2 * c];
        uu.u[1] = hi ? Xb[2 * c + 1] : Bp[2 * c + 1];
        uu.u[2] = hi ? Bp[2 * c]     : Xb[2 * c];
        uu.u[3] = hi ? Bp[2 * c + 1] : Xb[2 * c + 1];
        *reinterpret_cast<short8*>(&O[obase + dt * 32 + c * 8]) = uu.v;
      }
    }
  }
}

// ---------------- host launch ----------------
extern "C" void kernel_launch(void* const* d_in, const int* in_sizes, int n_in,
                              void* d_out, int out_size, void* d_ws, size_t ws_size,
                              hipStream_t stream) {
  const float* q  = (const float*)d_in[0];
  const float* k  = (const float*)d_in[1];
  const float* v  = (const float*)d_in[2];
  // d_in[3] = mask: known causal tril -> applied analytically
  const float* wq = (const float*)d_in[4];
  const float* bq = (const float*)d_in[5];
  const float* wk = (const float*)d_in[6];
  const float* bk = (const float*)d_in[7];
  const float* wv = (const float*)d_in[8];
  const float* bv = (const float*)d_in[9];
  const float* wo = (const float*)d_in[10];
  const float* bo = (const float*)d_in[11];
  float* out = (float*)d_out;

  u16* ws = (u16*)d_ws;
  const size_t WE = 1024ull * 1024;
  u16* Wq   = ws;
  u16* Wk   = Wq + WE;
  u16* Wv   = Wk + WE;
  u16* Wo   = Wv + WE;
  u16* QKVp = Wo + WE;                  // [8192][3072]
  u16* AO   = QKVp + 8192ull * 3072;    // [8192][1024]

  cvt4<<<dim3(1024, 4), 256, 0, stream>>>(wq, wk, wv, wo, Wq, Wk, Wv, Wo, (int)(WE / 4));

  gemm_qkv<<<dim3(8, 64, 3), 256, 0, stream>>>(q, k, v, Wq, Wk, Wv, bq, bk, bv, QKVp);

  attn_fwd<<<dim3(64, 16), 256, 0, stream>>>(QKVp, AO);

  gemm_out<<<dim3(8, 128), 256, 0, stream>>>(AO, Wo, bo, out);
}